// Round 1
// baseline (5557.405 us; speedup 1.0000x reference)
//
#include <hip/hip_runtime.h>

// ---------------------------------------------------------------------------
// HOTFormerStage — round 1: full fused-block implementation.
// NB=2 blocks; per block: CPE+LN1 -> QKV gemm -> windowed attention ->
// proj gemm -> resid+LN2 -> MLP1(gelu) -> MLP2 -> resid + output scatter.
// All GEMMs: bf16 MFMA 16x16x32, f32 accum. Residual stream x kept in f32
// (the only numerically-live path given layer-scale gamma=1e-5).
// ---------------------------------------------------------------------------

#define NW_    8192
#define KWIN   32
#define SEQ    33
#define NTOK   262144      // NW_*KWIN
#define MROWS  270336      // NW_*SEQ
#define CDIM   256
#define HEADS  8
#define HIDD   1024

typedef unsigned short u16;
typedef __attribute__((ext_vector_type(8))) short short8;
typedef __attribute__((ext_vector_type(4))) float f32x4;

__device__ __forceinline__ u16 f2bf(float f) {
    unsigned int u = __builtin_bit_cast(unsigned int, f);
    u += 0x7FFFu + ((u >> 16) & 1u);          // RNE
    return (u16)(u >> 16);
}
__device__ __forceinline__ float bf2f(u16 h) {
    return __builtin_bit_cast(float, (unsigned int)h << 16);
}
__device__ __forceinline__ float wsum(float v) {
#pragma unroll
    for (int off = 32; off > 0; off >>= 1) v += __shfl_xor(v, off);
    return v;
}
__device__ __forceinline__ float gelu_f(float v) {
    float t = tanhf(0.7978845608028654f * (v + 0.044715f * v * v * v));
    return 0.5f * v * (1.0f + t);
}
__device__ __forceinline__ void gload_lds16(const void* g, void* l) {
    __builtin_amdgcn_global_load_lds(
        (const __attribute__((address_space(1))) unsigned int*)g,
        (__attribute__((address_space(3))) unsigned int*)l, 16, 0, 0);
}

// ---------------------------------------------------------------------------
// K0: weight convert + transpose  W[K][N] f32 -> Wt[N][K] bf16
// ---------------------------------------------------------------------------
__global__ __launch_bounds__(256) void transpose_bf16_kernel(
    const float* __restrict__ W, u16* __restrict__ Wt, int K, int N)
{
    int idx = blockIdx.x * 256 + threadIdx.x;
    if (idx >= K * N) return;
    int n = idx / K, k = idx - n * K;
    Wt[idx] = f2bf(W[(size_t)k * N + n]);
}

// ---------------------------------------------------------------------------
// K1: x = concat(rt, data + cpe_conv(data)); h = LN1(x) in bf16
// one wave per row (64 lanes x 4 channels)
// ---------------------------------------------------------------------------
__global__ __launch_bounds__(256) void cpe_ln1_kernel(
    const float* __restrict__ data, const float* __restrict__ rt,
    const float* __restrict__ cpe_w, const float* __restrict__ cpe_b,
    const float* __restrict__ ln_g, const float* __restrict__ ln_b,
    float* __restrict__ x, u16* __restrict__ h)
{
    const int lane = threadIdx.x & 63, wid = threadIdx.x >> 6;
    const int row = blockIdx.x * 4 + wid;
    const int w = row / SEQ, s = row - w * SEQ;
    const int c0 = lane * 4;
    float4 xv;
    if (s == 0) {
        xv = *(const float4*)(rt + (size_t)w * CDIM + c0);
    } else {
        const long t = (long)w * KWIN + s - 1;
        const float4 a = *(const float4*)(data + t * CDIM + c0);
        float4 am = {0.f, 0.f, 0.f, 0.f}, ap = {0.f, 0.f, 0.f, 0.f};
        if (t > 0)        am = *(const float4*)(data + (t - 1) * CDIM + c0);
        if (t < NTOK - 1) ap = *(const float4*)(data + (t + 1) * CDIM + c0);
        const float4 w0 = *(const float4*)(cpe_w + 0 * CDIM + c0);
        const float4 w1 = *(const float4*)(cpe_w + 1 * CDIM + c0);
        const float4 w2 = *(const float4*)(cpe_w + 2 * CDIM + c0);
        const float4 cb = *(const float4*)(cpe_b + c0);
        xv.x = a.x + am.x * w0.x + a.x * w1.x + ap.x * w2.x + cb.x;
        xv.y = a.y + am.y * w0.y + a.y * w1.y + ap.y * w2.y + cb.y;
        xv.z = a.z + am.z * w0.z + a.z * w1.z + ap.z * w2.z + cb.z;
        xv.w = a.w + am.w * w0.w + a.w * w1.w + ap.w * w2.w + cb.w;
    }
    float s1 = wsum(xv.x + xv.y + xv.z + xv.w);
    float s2 = wsum(xv.x * xv.x + xv.y * xv.y + xv.z * xv.z + xv.w * xv.w);
    const float mean = s1 * (1.f / 256.f);
    const float var  = s2 * (1.f / 256.f) - mean * mean;
    const float rs   = rsqrtf(var + 1e-5f);
    const float4 g = *(const float4*)(ln_g + c0);
    const float4 b = *(const float4*)(ln_b + c0);
    *(float4*)(x + (size_t)row * CDIM + c0) = xv;
    ushort4 hv;
    hv.x = f2bf((xv.x - mean) * rs * g.x + b.x);
    hv.y = f2bf((xv.y - mean) * rs * g.y + b.y);
    hv.z = f2bf((xv.z - mean) * rs * g.z + b.z);
    hv.w = f2bf((xv.w - mean) * rs * g.w + b.w);
    *(ushort4*)(h + (size_t)row * CDIM + c0) = hv;
}

// ---------------------------------------------------------------------------
// GEMM: C[M][NT] = act(A[M][KT] @ Bt[NT][KT]^T + bias), bf16 in/out, f32 acc
// 128x128 tile, 4 waves (2x2 of 64x64), mfma 16x16x32, BK=64
// ---------------------------------------------------------------------------
template<int KT, int NT, bool GELU>
__global__ __launch_bounds__(256) void gemm_kernel(
    const u16* __restrict__ A, const u16* __restrict__ Bt,
    const float* __restrict__ bias, u16* __restrict__ Cout)
{
    __shared__ u16 As[128 * 64];
    __shared__ u16 Bs[128 * 64];
    const int lane = threadIdx.x & 63, wid = threadIdx.x >> 6;
    const int row0 = blockIdx.y * 128, col0 = blockIdx.x * 128;
    const int wr = (wid >> 1) * 64, wc = (wid & 1) * 64;
    const int lr = lane & 15, lk = (lane >> 4) * 8;
    f32x4 acc[4][4] = {};
    for (int k0 = 0; k0 < KT; k0 += 64) {
        __syncthreads();
#pragma unroll
        for (int cc = 0; cc < 4; ++cc) {
            const int g = wid * 4 + cc;
            const int chunk = g * 64 + lane;
            const int r = chunk >> 3, c8 = chunk & 7;
            gload_lds16(A + (size_t)(row0 + r) * KT + k0 + c8 * 8, (char*)As + g * 1024);
            gload_lds16(Bt + (size_t)(col0 + r) * KT + k0 + c8 * 8, (char*)Bs + g * 1024);
        }
        __syncthreads();
#pragma unroll
        for (int kk = 0; kk < 2; ++kk) {
            short8 a[4], b[4];
#pragma unroll
            for (int m = 0; m < 4; ++m)
                a[m] = *(const short8*)(As + (wr + m * 16 + lr) * 64 + kk * 32 + lk);
#pragma unroll
            for (int n = 0; n < 4; ++n)
                b[n] = *(const short8*)(Bs + (wc + n * 16 + lr) * 64 + kk * 32 + lk);
#pragma unroll
            for (int m = 0; m < 4; ++m)
#pragma unroll
                for (int n = 0; n < 4; ++n)
                    acc[m][n] = __builtin_amdgcn_mfma_f32_16x16x32_bf16(
                        a[m], b[n], acc[m][n], 0, 0, 0);
        }
    }
    const int l4 = (lane >> 4) * 4;
#pragma unroll
    for (int n = 0; n < 4; ++n) {
        const int col = col0 + wc + n * 16 + lr;
        const float bv = bias[col];
#pragma unroll
        for (int m = 0; m < 4; ++m) {
#pragma unroll
            for (int r = 0; r < 4; ++r) {
                const int row = row0 + wr + m * 16 + l4 + r;
                float v = acc[m][n][r] + bv;
                if (GELU) v = gelu_f(v);
                Cout[(size_t)row * NT + col] = f2bf(v);
            }
        }
    }
}

// ---------------------------------------------------------------------------
// K3: windowed attention, one wave per (window, head). q/k/v staged in LDS.
// ---------------------------------------------------------------------------
__global__ __launch_bounds__(256) void attn_kernel(
    const u16* __restrict__ qkv, const float* __restrict__ rpe,
    u16* __restrict__ o)
{
    __shared__ float sm[4 * 3300];
    const int lane = threadIdx.x & 63, wid = threadIdx.x >> 6;
    float* qs = sm + wid * 3300;
    float* ks = qs + 1089;
    float* vs = ks + 1089;
    float* rowbuf = vs + 1089;   // 33 floats
    const int task = blockIdx.x * 4 + wid;
    const int w = task >> 3, hh = task & 7;
    const u16* base = qkv + (size_t)(w * SEQ) * 768 + hh * 32;
    for (int idx = lane; idx < SEQ * 32; idx += 64) {
        const int s = idx >> 5, d = idx & 31;
        qs[s * 33 + d] = bf2f(base[(size_t)s * 768 + d]);
        ks[s * 33 + d] = bf2f(base[(size_t)s * 768 + 256 + d]);
        vs[s * 33 + d] = bf2f(base[(size_t)s * 768 + 512 + d]);
    }
    const float* rp = rpe + hh * SEQ * SEQ;
    const float scale = 0.17677669529663687f;
    for (int s = 0; s < SEQ; ++s) {
        float sc = -1e30f;
        if (lane < SEQ) {
            float a = 0.f;
#pragma unroll
            for (int d = 0; d < 32; ++d) a += qs[s * 33 + d] * ks[lane * 33 + d];
            sc = a * scale + rp[s * SEQ + lane];
        }
        float mx = sc;
#pragma unroll
        for (int off = 32; off > 0; off >>= 1) mx = fmaxf(mx, __shfl_xor(mx, off));
        const float e = (lane < SEQ) ? __expf(sc - mx) : 0.f;
        float sum = e;
#pragma unroll
        for (int off = 32; off > 0; off >>= 1) sum += __shfl_xor(sum, off);
        const float inv = 1.f / sum;
        if (lane < SEQ) rowbuf[lane] = e * inv;
        if (lane < 32) {
            float a = 0.f;
#pragma unroll
            for (int j = 0; j < SEQ; ++j) a += rowbuf[j] * vs[j * 33 + lane];
            o[(size_t)(w * SEQ + s) * CDIM + hh * 32 + lane] = f2bf(a);
        }
    }
}

// ---------------------------------------------------------------------------
// K5: x += gamma1 * p ; h2 = LN2(x) bf16
// ---------------------------------------------------------------------------
__global__ __launch_bounds__(256) void resid_ln2_kernel(
    const u16* __restrict__ p, const float* __restrict__ gamma,
    const float* __restrict__ ln_g, const float* __restrict__ ln_b,
    float* __restrict__ x, u16* __restrict__ h)
{
    const int lane = threadIdx.x & 63, wid = threadIdx.x >> 6;
    const int row = blockIdx.x * 4 + wid;
    const int c0 = lane * 4;
    float4 xv = *(const float4*)(x + (size_t)row * CDIM + c0);
    const ushort4 pv = *(const ushort4*)(p + (size_t)row * CDIM + c0);
    const float4 gm = *(const float4*)(gamma + c0);
    xv.x += gm.x * bf2f(pv.x);
    xv.y += gm.y * bf2f(pv.y);
    xv.z += gm.z * bf2f(pv.z);
    xv.w += gm.w * bf2f(pv.w);
    float s1 = wsum(xv.x + xv.y + xv.z + xv.w);
    float s2 = wsum(xv.x * xv.x + xv.y * xv.y + xv.z * xv.z + xv.w * xv.w);
    const float mean = s1 * (1.f / 256.f);
    const float var  = s2 * (1.f / 256.f) - mean * mean;
    const float rs   = rsqrtf(var + 1e-5f);
    const float4 g = *(const float4*)(ln_g + c0);
    const float4 b = *(const float4*)(ln_b + c0);
    *(float4*)(x + (size_t)row * CDIM + c0) = xv;
    ushort4 hv;
    hv.x = f2bf((xv.x - mean) * rs * g.x + b.x);
    hv.y = f2bf((xv.y - mean) * rs * g.y + b.y);
    hv.z = f2bf((xv.z - mean) * rs * g.z + b.z);
    hv.w = f2bf((xv.w - mean) * rs * g.w + b.w);
    *(ushort4*)(h + (size_t)row * CDIM + c0) = hv;
}

// ---------------------------------------------------------------------------
// K8: xn = x + gamma2 * f2 ; scatter to d_out {data[N][C], rt[NW][C]}
// ---------------------------------------------------------------------------
__global__ __launch_bounds__(256) void resid_out_kernel(
    const u16* __restrict__ f2, const float* __restrict__ gamma,
    const float* __restrict__ x, float* __restrict__ out)
{
    const int lane = threadIdx.x & 63, wid = threadIdx.x >> 6;
    const int row = blockIdx.x * 4 + wid;
    const int w = row / SEQ, s = row - w * SEQ;
    const int c0 = lane * 4;
    float4 xv = *(const float4*)(x + (size_t)row * CDIM + c0);
    const ushort4 fv = *(const ushort4*)(f2 + (size_t)row * CDIM + c0);
    const float4 gm = *(const float4*)(gamma + c0);
    xv.x += gm.x * bf2f(fv.x);
    xv.y += gm.y * bf2f(fv.y);
    xv.z += gm.z * bf2f(fv.z);
    xv.w += gm.w * bf2f(fv.w);
    float* dst = (s == 0)
        ? out + (size_t)NTOK * CDIM + (size_t)w * CDIM + c0
        : out + (size_t)(w * KWIN + s - 1) * CDIM + c0;
    *(float4*)dst = xv;
}

// ---------------------------------------------------------------------------
extern "C" void kernel_launch(void* const* d_in, const int* in_sizes, int n_in,
                              void* d_out, int out_size, void* d_ws, size_t ws_size,
                              hipStream_t stream)
{
    const float* data0  = (const float*)d_in[0];
    const float* rt0    = (const float*)d_in[1];
    const float* cpe_w  = (const float*)d_in[2];
    const float* cpe_b  = (const float*)d_in[3];
    const float* ln1_g  = (const float*)d_in[4];
    const float* ln1_b  = (const float*)d_in[5];
    const float* qkv_w  = (const float*)d_in[6];
    const float* qkv_b  = (const float*)d_in[7];
    const float* rpe    = (const float*)d_in[8];
    const float* proj_w = (const float*)d_in[9];
    const float* proj_b = (const float*)d_in[10];
    const float* ln2_g  = (const float*)d_in[11];
    const float* ln2_b  = (const float*)d_in[12];
    const float* w1     = (const float*)d_in[13];
    const float* b1     = (const float*)d_in[14];
    const float* w2     = (const float*)d_in[15];
    const float* b2     = (const float*)d_in[16];
    const float* g1     = (const float*)d_in[17];
    const float* g2     = (const float*)d_in[18];
    float* out = (float*)d_out;

    // workspace layout (bytes): regionA 553,648,128 | regionB 138,412,032 |
    // x 276,824,064 | bf16 weights ~3.1 MB  => ~972 MB total
    char* ws = (char*)d_ws;
    u16*   regA = (u16*)ws;
    u16*   regB = (u16*)(ws + 553648128ull);
    float* x    = (float*)(ws + 692060160ull);
    u16*   wq_t = (u16*)(ws + 968884224ull);
    u16*   wp_t = (u16*)(ws + 969670656ull);
    u16*   w1_t = (u16*)(ws + 969932800ull);
    u16*   w2_t = (u16*)(ws + 970981376ull);

    for (int i = 0; i < 2; ++i) {
        transpose_bf16_kernel<<<(256 * 768 + 255) / 256, 256, 0, stream>>>(
            qkv_w + (size_t)i * 256 * 768, wq_t + (size_t)i * 768 * 256, 256, 768);
        transpose_bf16_kernel<<<(256 * 256 + 255) / 256, 256, 0, stream>>>(
            proj_w + (size_t)i * 256 * 256, wp_t + (size_t)i * 256 * 256, 256, 256);
        transpose_bf16_kernel<<<(256 * 1024 + 255) / 256, 256, 0, stream>>>(
            w1 + (size_t)i * 256 * 1024, w1_t + (size_t)i * 1024 * 256, 256, 1024);
        transpose_bf16_kernel<<<(256 * 1024 + 255) / 256, 256, 0, stream>>>(
            w2 + (size_t)i * 1024 * 256, w2_t + (size_t)i * 256 * 1024, 1024, 256);
    }

    for (int i = 0; i < 2; ++i) {
        const float* dsrc = (i == 0) ? data0 : out;
        const float* rsrc = (i == 0) ? rt0 : out + (size_t)NTOK * CDIM;

        cpe_ln1_kernel<<<MROWS / 4, 256, 0, stream>>>(
            dsrc, rsrc, cpe_w + (size_t)i * 3 * 256, cpe_b + (size_t)i * 256,
            ln1_g + (size_t)i * 256, ln1_b + (size_t)i * 256, x, regB);

        gemm_kernel<256, 768, false><<<dim3(6, MROWS / 128), 256, 0, stream>>>(
            regB, wq_t + (size_t)i * 768 * 256, qkv_b + (size_t)i * 768, regA);

        attn_kernel<<<NW_ * HEADS / 4, 256, 0, stream>>>(
            regA, rpe + (size_t)i * HEADS * SEQ * SEQ, regB);

        gemm_kernel<256, 256, false><<<dim3(2, MROWS / 128), 256, 0, stream>>>(
            regB, wp_t + (size_t)i * 256 * 256, proj_b + (size_t)i * 256, regA);

        resid_ln2_kernel<<<MROWS / 4, 256, 0, stream>>>(
            regA, g1 + (size_t)i * 256, ln2_g + (size_t)i * 256,
            ln2_b + (size_t)i * 256, x, regB);

        gemm_kernel<256, 1024, true><<<dim3(8, MROWS / 128), 256, 0, stream>>>(
            regB, w1_t + (size_t)i * 1024 * 256, b1 + (size_t)i * 1024, regA);

        gemm_kernel<1024, 256, false><<<dim3(2, MROWS / 128), 256, 0, stream>>>(
            regA, w2_t + (size_t)i * 256 * 1024, b2 + (size_t)i * 256, regB);

        resid_out_kernel<<<MROWS / 4, 256, 0, stream>>>(
            regB, g2 + (size_t)i * 256, x, out);
    }
}

// Round 2
// 3434.358 us; speedup vs baseline: 1.6182x; 1.6182x over previous
//
#include <hip/hip_runtime.h>

// ---------------------------------------------------------------------------
// HOTFormerStage — round 2: MFMA attention (was scalar, 49% of runtime).
// NB=2 blocks; per block: CPE+LN1 -> QKV gemm -> windowed MFMA attention ->
// proj gemm -> resid+LN2 -> MLP1(gelu) -> MLP2 -> resid + output scatter.
// ---------------------------------------------------------------------------

#define NW_    8192
#define KWIN   32
#define SEQ    33
#define NTOK   262144      // NW_*KWIN
#define MROWS  270336      // NW_*SEQ
#define CDIM   256
#define HEADS  8
#define HIDD   1024

typedef unsigned short u16;
typedef __attribute__((ext_vector_type(8))) short short8;
typedef __attribute__((ext_vector_type(4))) float f32x4;

__device__ __forceinline__ u16 f2bf(float f) {
    unsigned int u = __builtin_bit_cast(unsigned int, f);
    u += 0x7FFFu + ((u >> 16) & 1u);          // RNE
    return (u16)(u >> 16);
}
__device__ __forceinline__ float bf2f(u16 h) {
    return __builtin_bit_cast(float, (unsigned int)h << 16);
}
__device__ __forceinline__ float wsum(float v) {
#pragma unroll
    for (int off = 32; off > 0; off >>= 1) v += __shfl_xor(v, off);
    return v;
}
__device__ __forceinline__ float gelu_f(float v) {
    float t = tanhf(0.7978845608028654f * (v + 0.044715f * v * v * v));
    return 0.5f * v * (1.0f + t);
}
__device__ __forceinline__ void gload_lds16(const void* g, void* l) {
    __builtin_amdgcn_global_load_lds(
        (const __attribute__((address_space(1))) unsigned int*)g,
        (__attribute__((address_space(3))) unsigned int*)l, 16, 0, 0);
}

// ---------------------------------------------------------------------------
// K0: weight convert + transpose  W[K][N] f32 -> Wt[N][K] bf16
// ---------------------------------------------------------------------------
__global__ __launch_bounds__(256) void transpose_bf16_kernel(
    const float* __restrict__ W, u16* __restrict__ Wt, int K, int N)
{
    int idx = blockIdx.x * 256 + threadIdx.x;
    if (idx >= K * N) return;
    int n = idx / K, k = idx - n * K;
    Wt[idx] = f2bf(W[(size_t)k * N + n]);
}

// ---------------------------------------------------------------------------
// K1: x = concat(rt, data + cpe_conv(data)); h = LN1(x) in bf16
// ---------------------------------------------------------------------------
__global__ __launch_bounds__(256) void cpe_ln1_kernel(
    const float* __restrict__ data, const float* __restrict__ rt,
    const float* __restrict__ cpe_w, const float* __restrict__ cpe_b,
    const float* __restrict__ ln_g, const float* __restrict__ ln_b,
    float* __restrict__ x, u16* __restrict__ h)
{
    const int lane = threadIdx.x & 63, wid = threadIdx.x >> 6;
    const int row = blockIdx.x * 4 + wid;
    const int w = row / SEQ, s = row - w * SEQ;
    const int c0 = lane * 4;
    float4 xv;
    if (s == 0) {
        xv = *(const float4*)(rt + (size_t)w * CDIM + c0);
    } else {
        const long t = (long)w * KWIN + s - 1;
        const float4 a = *(const float4*)(data + t * CDIM + c0);
        float4 am = {0.f, 0.f, 0.f, 0.f}, ap = {0.f, 0.f, 0.f, 0.f};
        if (t > 0)        am = *(const float4*)(data + (t - 1) * CDIM + c0);
        if (t < NTOK - 1) ap = *(const float4*)(data + (t + 1) * CDIM + c0);
        const float4 w0 = *(const float4*)(cpe_w + 0 * CDIM + c0);
        const float4 w1 = *(const float4*)(cpe_w + 1 * CDIM + c0);
        const float4 w2 = *(const float4*)(cpe_w + 2 * CDIM + c0);
        const float4 cb = *(const float4*)(cpe_b + c0);
        xv.x = a.x + am.x * w0.x + a.x * w1.x + ap.x * w2.x + cb.x;
        xv.y = a.y + am.y * w0.y + a.y * w1.y + ap.y * w2.y + cb.y;
        xv.z = a.z + am.z * w0.z + a.z * w1.z + ap.z * w2.z + cb.z;
        xv.w = a.w + am.w * w0.w + a.w * w1.w + ap.w * w2.w + cb.w;
    }
    float s1 = wsum(xv.x + xv.y + xv.z + xv.w);
    float s2 = wsum(xv.x * xv.x + xv.y * xv.y + xv.z * xv.z + xv.w * xv.w);
    const float mean = s1 * (1.f / 256.f);
    const float var  = s2 * (1.f / 256.f) - mean * mean;
    const float rs   = rsqrtf(var + 1e-5f);
    const float4 g = *(const float4*)(ln_g + c0);
    const float4 b = *(const float4*)(ln_b + c0);
    *(float4*)(x + (size_t)row * CDIM + c0) = xv;
    ushort4 hv;
    hv.x = f2bf((xv.x - mean) * rs * g.x + b.x);
    hv.y = f2bf((xv.y - mean) * rs * g.y + b.y);
    hv.z = f2bf((xv.z - mean) * rs * g.z + b.z);
    hv.w = f2bf((xv.w - mean) * rs * g.w + b.w);
    *(ushort4*)(h + (size_t)row * CDIM + c0) = hv;
}

// ---------------------------------------------------------------------------
// GEMM: C[M][NT] = act(A[M][KT] @ Bt[NT][KT]^T + bias), bf16 in/out, f32 acc
// ---------------------------------------------------------------------------
template<int KT, int NT, bool GELU>
__global__ __launch_bounds__(256) void gemm_kernel(
    const u16* __restrict__ A, const u16* __restrict__ Bt,
    const float* __restrict__ bias, u16* __restrict__ Cout)
{
    __shared__ u16 As[128 * 64];
    __shared__ u16 Bs[128 * 64];
    const int lane = threadIdx.x & 63, wid = threadIdx.x >> 6;
    const int row0 = blockIdx.y * 128, col0 = blockIdx.x * 128;
    const int wr = (wid >> 1) * 64, wc = (wid & 1) * 64;
    const int lr = lane & 15, lk = (lane >> 4) * 8;
    f32x4 acc[4][4] = {};
    for (int k0 = 0; k0 < KT; k0 += 64) {
        __syncthreads();
#pragma unroll
        for (int cc = 0; cc < 4; ++cc) {
            const int g = wid * 4 + cc;
            const int chunk = g * 64 + lane;
            const int r = chunk >> 3, c8 = chunk & 7;
            gload_lds16(A + (size_t)(row0 + r) * KT + k0 + c8 * 8, (char*)As + g * 1024);
            gload_lds16(Bt + (size_t)(col0 + r) * KT + k0 + c8 * 8, (char*)Bs + g * 1024);
        }
        __syncthreads();
#pragma unroll
        for (int kk = 0; kk < 2; ++kk) {
            short8 a[4], b[4];
#pragma unroll
            for (int m = 0; m < 4; ++m)
                a[m] = *(const short8*)(As + (wr + m * 16 + lr) * 64 + kk * 32 + lk);
#pragma unroll
            for (int n = 0; n < 4; ++n)
                b[n] = *(const short8*)(Bs + (wc + n * 16 + lr) * 64 + kk * 32 + lk);
#pragma unroll
            for (int m = 0; m < 4; ++m)
#pragma unroll
                for (int n = 0; n < 4; ++n)
                    acc[m][n] = __builtin_amdgcn_mfma_f32_16x16x32_bf16(
                        a[m], b[n], acc[m][n], 0, 0, 0);
        }
    }
    const int l4 = (lane >> 4) * 4;
#pragma unroll
    for (int n = 0; n < 4; ++n) {
        const int col = col0 + wc + n * 16 + lr;
        const float bv = bias[col];
#pragma unroll
        for (int m = 0; m < 4; ++m) {
#pragma unroll
            for (int r = 0; r < 4; ++r) {
                const int row = row0 + wr + m * 16 + l4 + r;
                float v = acc[m][n][r] + bv;
                if (GELU) v = gelu_f(v);
                Cout[(size_t)row * NT + col] = f2bf(v);
            }
        }
    }
}

// ---------------------------------------------------------------------------
// K3: MFMA windowed attention. One wave per (window, head). S=33 padded to 48.
// QK^T: 9 mfma_16x16x32; softmax wave-parallel in C-layout; PV: 12 mfma.
// Per-wave LDS (u16): Q[48][40]@0, K[48][40]@1920, P[48][72]@0 (overlaps Q+K),
// Vt[32][72]@3840. Strides 40/72 shorts keep frag ds_read_b128 ~2-way (free).
// No __syncthreads: buffers are per-wave; same-wave DS ops are in-order.
// ---------------------------------------------------------------------------
__global__ __launch_bounds__(256) void attn_mfma_kernel(
    const u16* __restrict__ qkv, const float* __restrict__ rpe,
    u16* __restrict__ o)
{
    __shared__ u16 sm[4 * 6144];
    const int lane = threadIdx.x & 63, wid = threadIdx.x >> 6;
    u16* Qs = sm + wid * 6144;
    u16* Ks = Qs + 1920;
    u16* Ps = Qs;                 // overlaps Q+K (dead after QK^T frag reads)
    u16* Vt = Qs + 3840;
    const int task = blockIdx.x * 4 + wid;
    const int w = task >> 3, hh = task & 7;
    const u16* base = qkv + (size_t)(w * SEQ) * 768 + hh * 32;

    // zero Vt fully (pad cols must be 0, not garbage: 0*NaN = NaN in MFMA)
#pragma unroll
    for (int it = 0; it < 5; ++it) {
        int idx = it * 64 + lane;
        if (idx < 288) *(short8*)(Vt + idx * 8) = (short8)0;
    }
    // zero Q,K pad rows 33..47 (15 rows x 5 chunks, x2 matrices)
#pragma unroll
    for (int it = 0; it < 3; ++it) {
        int idx = it * 64 + lane;
        if (idx < 150) {
            int m = idx >= 75;
            int r = idx - m * 75;
            int s = 33 + r / 5, c = r - (r / 5) * 5;
            *(short8*)((m ? Ks : Qs) + s * 40 + c * 8) = (short8)0;
        }
    }
    // stage Q,K (33 rows x 4 chunks of 8 shorts)
#pragma unroll
    for (int it = 0; it < 3; ++it) {
        int idx = it * 64 + lane;
        if (idx < 132) {
            int s = idx >> 2, c = idx & 3;
            *(short8*)(Qs + s * 40 + c * 8) = *(const short8*)(base + (size_t)s * 768 + c * 8);
            *(short8*)(Ks + s * 40 + c * 8) = *(const short8*)(base + (size_t)s * 768 + 256 + c * 8);
        }
    }
    // stage V transposed: Vt[d][k] = V[k][d]
#pragma unroll
    for (int it = 0; it < 3; ++it) {
        int idx = it * 64 + lane;
        if (idx < 132) {
            int k = idx >> 2, c = idx & 3;
            short8 v = *(const short8*)(base + (size_t)k * 768 + 512 + c * 8);
#pragma unroll
            for (int j = 0; j < 8; ++j) Vt[(c * 8 + j) * 72 + k] = v[j];
        }
    }

    const int lr = lane & 15, lg = lane >> 4;
    // QK^T fragments (A: m=lr row, k=lg*8+j ; B: n=lr key, k=lg*8+j)
    short8 qa[3], kb[3];
#pragma unroll
    for (int mi = 0; mi < 3; ++mi)
        qa[mi] = *(const short8*)(Qs + (mi * 16 + lr) * 40 + lg * 8);
#pragma unroll
    for (int ni = 0; ni < 3; ++ni)
        kb[ni] = *(const short8*)(Ks + (ni * 16 + lr) * 40 + lg * 8);
    f32x4 sc[3][3];
#pragma unroll
    for (int mi = 0; mi < 3; ++mi)
#pragma unroll
        for (int ni = 0; ni < 3; ++ni) {
            f32x4 z = {0.f, 0.f, 0.f, 0.f};
            sc[mi][ni] = __builtin_amdgcn_mfma_f32_16x16x32_bf16(qa[mi], kb[ni], z, 0, 0, 0);
        }

    // zero P cols 48..63 (issued after frag reads; in-order DS makes it safe)
    {
        int idx = lane;
        if (idx < 48) {
            *(short8*)(Ps + idx * 72 + 48) = (short8)0;
            *(short8*)(Ps + idx * 72 + 56) = (short8)0;
        }
    }

    // softmax: score row (row = mi*16+lg*4+q) lives across 16 lanes (lr=col)
    const float* rp = rpe + hh * SEQ * SEQ;
    const float scale = 0.17677669529663687f;
#pragma unroll
    for (int mi = 0; mi < 3; ++mi) {
#pragma unroll
        for (int q = 0; q < 4; ++q) {
            const int row = mi * 16 + lg * 4 + q;
            const bool rv_ok = (row < 33);
            float r0 = rv_ok ? rp[row * 33 + lr] : 0.f;
            float r1 = rv_ok ? rp[row * 33 + 16 + lr] : 0.f;
            float r2 = (rv_ok && lr == 0) ? rp[row * 33 + 32] : 0.f;
            float s0 = sc[mi][0][q] * scale + r0;
            float s1 = sc[mi][1][q] * scale + r1;
            float s2 = (lr == 0) ? sc[mi][2][q] * scale + r2 : -1e30f;
            float m = fmaxf(fmaxf(s0, s1), s2);
#pragma unroll
            for (int off = 1; off < 16; off <<= 1) m = fmaxf(m, __shfl_xor(m, off));
            float e0 = __expf(s0 - m), e1 = __expf(s1 - m), e2 = __expf(s2 - m);
            float sum = e0 + e1 + e2;
#pragma unroll
            for (int off = 1; off < 16; off <<= 1) sum += __shfl_xor(sum, off);
            const float inv = 1.f / sum;
            Ps[row * 72 + lr]      = f2bf(e0 * inv);
            Ps[row * 72 + 16 + lr] = f2bf(e1 * inv);
            Ps[row * 72 + 32 + lr] = f2bf(e2 * inv);
        }
    }

    // PV: O[48][32] = P[48][64] x V[64][32] (pad k cols are exact zeros)
    f32x4 oacc[3][2] = {};
#pragma unroll
    for (int ks = 0; ks < 2; ++ks) {
        short8 pa[3], vb[2];
#pragma unroll
        for (int mi = 0; mi < 3; ++mi)
            pa[mi] = *(const short8*)(Ps + (mi * 16 + lr) * 72 + ks * 32 + lg * 8);
#pragma unroll
        for (int ni = 0; ni < 2; ++ni)
            vb[ni] = *(const short8*)(Vt + (ni * 16 + lr) * 72 + ks * 32 + lg * 8);
#pragma unroll
        for (int mi = 0; mi < 3; ++mi)
#pragma unroll
            for (int ni = 0; ni < 2; ++ni)
                oacc[mi][ni] = __builtin_amdgcn_mfma_f32_16x16x32_bf16(
                    pa[mi], vb[ni], oacc[mi][ni], 0, 0, 0);
    }

    // write O rows < 33
#pragma unroll
    for (int mi = 0; mi < 3; ++mi)
#pragma unroll
        for (int q = 0; q < 4; ++q) {
            const int row = mi * 16 + lg * 4 + q;
            if (row < 33) {
#pragma unroll
                for (int ni = 0; ni < 2; ++ni)
                    o[(size_t)(w * SEQ + row) * CDIM + hh * 32 + ni * 16 + lr] =
                        f2bf(oacc[mi][ni][q]);
            }
        }
}

// ---------------------------------------------------------------------------
// K5: x += gamma1 * p ; h2 = LN2(x) bf16
// ---------------------------------------------------------------------------
__global__ __launch_bounds__(256) void resid_ln2_kernel(
    const u16* __restrict__ p, const float* __restrict__ gamma,
    const float* __restrict__ ln_g, const float* __restrict__ ln_b,
    float* __restrict__ x, u16* __restrict__ h)
{
    const int lane = threadIdx.x & 63, wid = threadIdx.x >> 6;
    const int row = blockIdx.x * 4 + wid;
    const int c0 = lane * 4;
    float4 xv = *(const float4*)(x + (size_t)row * CDIM + c0);
    const ushort4 pv = *(const ushort4*)(p + (size_t)row * CDIM + c0);
    const float4 gm = *(const float4*)(gamma + c0);
    xv.x += gm.x * bf2f(pv.x);
    xv.y += gm.y * bf2f(pv.y);
    xv.z += gm.z * bf2f(pv.z);
    xv.w += gm.w * bf2f(pv.w);
    float s1 = wsum(xv.x + xv.y + xv.z + xv.w);
    float s2 = wsum(xv.x * xv.x + xv.y * xv.y + xv.z * xv.z + xv.w * xv.w);
    const float mean = s1 * (1.f / 256.f);
    const float var  = s2 * (1.f / 256.f) - mean * mean;
    const float rs   = rsqrtf(var + 1e-5f);
    const float4 g = *(const float4*)(ln_g + c0);
    const float4 b = *(const float4*)(ln_b + c0);
    *(float4*)(x + (size_t)row * CDIM + c0) = xv;
    ushort4 hv;
    hv.x = f2bf((xv.x - mean) * rs * g.x + b.x);
    hv.y = f2bf((xv.y - mean) * rs * g.y + b.y);
    hv.z = f2bf((xv.z - mean) * rs * g.z + b.z);
    hv.w = f2bf((xv.w - mean) * rs * g.w + b.w);
    *(ushort4*)(h + (size_t)row * CDIM + c0) = hv;
}

// ---------------------------------------------------------------------------
// K8: xn = x + gamma2 * f2 ; scatter to d_out {data[N][C], rt[NW][C]}
// ---------------------------------------------------------------------------
__global__ __launch_bounds__(256) void resid_out_kernel(
    const u16* __restrict__ f2, const float* __restrict__ gamma,
    const float* __restrict__ x, float* __restrict__ out)
{
    const int lane = threadIdx.x & 63, wid = threadIdx.x >> 6;
    const int row = blockIdx.x * 4 + wid;
    const int w = row / SEQ, s = row - w * SEQ;
    const int c0 = lane * 4;
    float4 xv = *(const float4*)(x + (size_t)row * CDIM + c0);
    const ushort4 fv = *(const ushort4*)(f2 + (size_t)row * CDIM + c0);
    const float4 gm = *(const float4*)(gamma + c0);
    xv.x += gm.x * bf2f(fv.x);
    xv.y += gm.y * bf2f(fv.y);
    xv.z += gm.z * bf2f(fv.z);
    xv.w += gm.w * bf2f(fv.w);
    float* dst = (s == 0)
        ? out + (size_t)NTOK * CDIM + (size_t)w * CDIM + c0
        : out + (size_t)(w * KWIN + s - 1) * CDIM + c0;
    *(float4*)dst = xv;
}

// ---------------------------------------------------------------------------
extern "C" void kernel_launch(void* const* d_in, const int* in_sizes, int n_in,
                              void* d_out, int out_size, void* d_ws, size_t ws_size,
                              hipStream_t stream)
{
    const float* data0  = (const float*)d_in[0];
    const float* rt0    = (const float*)d_in[1];
    const float* cpe_w  = (const float*)d_in[2];
    const float* cpe_b  = (const float*)d_in[3];
    const float* ln1_g  = (const float*)d_in[4];
    const float* ln1_b  = (const float*)d_in[5];
    const float* qkv_w  = (const float*)d_in[6];
    const float* qkv_b  = (const float*)d_in[7];
    const float* rpe    = (const float*)d_in[8];
    const float* proj_w = (const float*)d_in[9];
    const float* proj_b = (const float*)d_in[10];
    const float* ln2_g  = (const float*)d_in[11];
    const float* ln2_b  = (const float*)d_in[12];
    const float* w1     = (const float*)d_in[13];
    const float* b1     = (const float*)d_in[14];
    const float* w2     = (const float*)d_in[15];
    const float* b2     = (const float*)d_in[16];
    const float* g1     = (const float*)d_in[17];
    const float* g2     = (const float*)d_in[18];
    float* out = (float*)d_out;

    char* ws = (char*)d_ws;
    u16*   regA = (u16*)ws;
    u16*   regB = (u16*)(ws + 553648128ull);
    float* x    = (float*)(ws + 692060160ull);
    u16*   wq_t = (u16*)(ws + 968884224ull);
    u16*   wp_t = (u16*)(ws + 969670656ull);
    u16*   w1_t = (u16*)(ws + 969932800ull);
    u16*   w2_t = (u16*)(ws + 970981376ull);

    for (int i = 0; i < 2; ++i) {
        transpose_bf16_kernel<<<(256 * 768 + 255) / 256, 256, 0, stream>>>(
            qkv_w + (size_t)i * 256 * 768, wq_t + (size_t)i * 768 * 256, 256, 768);
        transpose_bf16_kernel<<<(256 * 256 + 255) / 256, 256, 0, stream>>>(
            proj_w + (size_t)i * 256 * 256, wp_t + (size_t)i * 256 * 256, 256, 256);
        transpose_bf16_kernel<<<(256 * 1024 + 255) / 256, 256, 0, stream>>>(
            w1 + (size_t)i * 256 * 1024, w1_t + (size_t)i * 1024 * 256, 256, 1024);
        transpose_bf16_kernel<<<(256 * 1024 + 255) / 256, 256, 0, stream>>>(
            w2 + (size_t)i * 1024 * 256, w2_t + (size_t)i * 256 * 1024, 1024, 256);
    }

    for (int i = 0; i < 2; ++i) {
        const float* dsrc = (i == 0) ? data0 : out;
        const float* rsrc = (i == 0) ? rt0 : out + (size_t)NTOK * CDIM;

        cpe_ln1_kernel<<<MROWS / 4, 256, 0, stream>>>(
            dsrc, rsrc, cpe_w + (size_t)i * 3 * 256, cpe_b + (size_t)i * 256,
            ln1_g + (size_t)i * 256, ln1_b + (size_t)i * 256, x, regB);

        gemm_kernel<256, 768, false><<<dim3(6, MROWS / 128), 256, 0, stream>>>(
            regB, wq_t + (size_t)i * 768 * 256, qkv_b + (size_t)i * 768, regA);

        attn_mfma_kernel<<<NW_ * HEADS / 4, 256, 0, stream>>>(
            regA, rpe + (size_t)i * HEADS * SEQ * SEQ, regB);

        gemm_kernel<256, 256, false><<<dim3(2, MROWS / 128), 256, 0, stream>>>(
            regB, wp_t + (size_t)i * 256 * 256, proj_b + (size_t)i * 256, regA);

        resid_ln2_kernel<<<MROWS / 4, 256, 0, stream>>>(
            regA, g1 + (size_t)i * 256, ln2_g + (size_t)i * 256,
            ln2_b + (size_t)i * 256, x, regB);

        gemm_kernel<256, 1024, true><<<dim3(8, MROWS / 128), 256, 0, stream>>>(
            regB, w1_t + (size_t)i * 1024 * 256, b1 + (size_t)i * 1024, regA);

        gemm_kernel<1024, 256, false><<<dim3(2, MROWS / 128), 256, 0, stream>>>(
            regA, w2_t + (size_t)i * 256 * 1024, b2 + (size_t)i * 256, regB);

        resid_out_kernel<<<MROWS / 4, 256, 0, stream>>>(
            regB, g2 + (size_t)i * 256, x, out);
    }
}

// Round 4
// 3040.160 us; speedup vs baseline: 1.8280x; 1.1297x over previous
//
#include <hip/hip_runtime.h>

// ---------------------------------------------------------------------------
// HOTFormerStage — round 4: fix round-3 epilogue bugs (only half the C tile
// was stored: 1024 chunks vs 2048; and Ct stride 132 gave misaligned
// ds_read_b128 -> stride 136). GEMM: T2 swizzle + dbuf pipeline + LDS-staged
// vector epilogue; fusions: proj->resid(x), mlp2->resid+scatter; x in bf16.
// ---------------------------------------------------------------------------

#define NW_    8192
#define KWIN   32
#define SEQ    33
#define NTOK   262144      // NW_*KWIN
#define MROWS  270336      // NW_*SEQ
#define CDIM   256
#define HEADS  8
#define HIDD   1024

typedef unsigned short u16;
typedef __attribute__((ext_vector_type(8))) short short8;
typedef __attribute__((ext_vector_type(4))) float f32x4;

__device__ __forceinline__ u16 f2bf(float f) {
    unsigned int u = __builtin_bit_cast(unsigned int, f);
    u += 0x7FFFu + ((u >> 16) & 1u);          // RNE
    return (u16)(u >> 16);
}
__device__ __forceinline__ float bf2f(u16 h) {
    return __builtin_bit_cast(float, (unsigned int)h << 16);
}
__device__ __forceinline__ float wsum(float v) {
#pragma unroll
    for (int off = 32; off > 0; off >>= 1) v += __shfl_xor(v, off);
    return v;
}
__device__ __forceinline__ float gelu_f(float v) {
    float t = tanhf(0.7978845608028654f * (v + 0.044715f * v * v * v));
    return 0.5f * v * (1.0f + t);
}
__device__ __forceinline__ void gload_lds16(const void* g, void* l) {
    __builtin_amdgcn_global_load_lds(
        (const __attribute__((address_space(1))) unsigned int*)g,
        (__attribute__((address_space(3))) unsigned int*)l, 16, 0, 0);
}
__device__ __forceinline__ float4 ld4bf(const u16* p) {
    ushort4 v = *(const ushort4*)p;
    return make_float4(bf2f(v.x), bf2f(v.y), bf2f(v.z), bf2f(v.w));
}

// ---------------------------------------------------------------------------
// K0: weight convert + transpose  W[K][N] f32 -> Wt[N][K] bf16
// ---------------------------------------------------------------------------
__global__ __launch_bounds__(256) void transpose_bf16_kernel(
    const float* __restrict__ W, u16* __restrict__ Wt, int K, int N)
{
    int idx = blockIdx.x * 256 + threadIdx.x;
    if (idx >= K * N) return;
    int n = idx / K, k = idx - n * K;
    Wt[idx] = f2bf(W[(size_t)k * N + n]);
}

// ---------------------------------------------------------------------------
// K1: x = concat(rt, data + cpe_conv(data)) [bf16]; h = LN1(x) [bf16]
// ---------------------------------------------------------------------------
template<bool BF>
__global__ __launch_bounds__(256) void cpe_ln1_kernel(
    const void* __restrict__ datav, const void* __restrict__ rtv,
    const float* __restrict__ cpe_w, const float* __restrict__ cpe_b,
    const float* __restrict__ ln_g, const float* __restrict__ ln_b,
    u16* __restrict__ x, u16* __restrict__ h)
{
    const int lane = threadIdx.x & 63, wid = threadIdx.x >> 6;
    const int row = blockIdx.x * 4 + wid;
    const int w = row / SEQ, s = row - w * SEQ;
    const int c0 = lane * 4;
    float4 xv;
    if (s == 0) {
        xv = BF ? ld4bf((const u16*)rtv + (size_t)w * CDIM + c0)
                : *(const float4*)((const float*)rtv + (size_t)w * CDIM + c0);
    } else {
        const long t = (long)w * KWIN + s - 1;
        float4 a, am = {0.f,0.f,0.f,0.f}, ap = {0.f,0.f,0.f,0.f};
        if (BF) {
            const u16* d = (const u16*)datav;
            a = ld4bf(d + t * CDIM + c0);
            if (t > 0)        am = ld4bf(d + (t - 1) * CDIM + c0);
            if (t < NTOK - 1) ap = ld4bf(d + (t + 1) * CDIM + c0);
        } else {
            const float* d = (const float*)datav;
            a = *(const float4*)(d + t * CDIM + c0);
            if (t > 0)        am = *(const float4*)(d + (t - 1) * CDIM + c0);
            if (t < NTOK - 1) ap = *(const float4*)(d + (t + 1) * CDIM + c0);
        }
        const float4 w0 = *(const float4*)(cpe_w + 0 * CDIM + c0);
        const float4 w1 = *(const float4*)(cpe_w + 1 * CDIM + c0);
        const float4 w2 = *(const float4*)(cpe_w + 2 * CDIM + c0);
        const float4 cb = *(const float4*)(cpe_b + c0);
        xv.x = a.x + am.x * w0.x + a.x * w1.x + ap.x * w2.x + cb.x;
        xv.y = a.y + am.y * w0.y + a.y * w1.y + ap.y * w2.y + cb.y;
        xv.z = a.z + am.z * w0.z + a.z * w1.z + ap.z * w2.z + cb.z;
        xv.w = a.w + am.w * w0.w + a.w * w1.w + ap.w * w2.w + cb.w;
    }
    float s1 = wsum(xv.x + xv.y + xv.z + xv.w);
    float s2 = wsum(xv.x * xv.x + xv.y * xv.y + xv.z * xv.z + xv.w * xv.w);
    const float mean = s1 * (1.f / 256.f);
    const float var  = s2 * (1.f / 256.f) - mean * mean;
    const float rs   = rsqrtf(var + 1e-5f);
    const float4 g = *(const float4*)(ln_g + c0);
    const float4 b = *(const float4*)(ln_b + c0);
    ushort4 xo;
    xo.x = f2bf(xv.x); xo.y = f2bf(xv.y); xo.z = f2bf(xv.z); xo.w = f2bf(xv.w);
    *(ushort4*)(x + (size_t)row * CDIM + c0) = xo;
    ushort4 hv;
    hv.x = f2bf((xv.x - mean) * rs * g.x + b.x);
    hv.y = f2bf((xv.y - mean) * rs * g.y + b.y);
    hv.z = f2bf((xv.z - mean) * rs * g.z + b.z);
    hv.w = f2bf((xv.w - mean) * rs * g.w + b.w);
    *(ushort4*)(h + (size_t)row * CDIM + c0) = hv;
}

// ---------------------------------------------------------------------------
// K_LN: h = LN(x) [bf16 -> bf16]
// ---------------------------------------------------------------------------
__global__ __launch_bounds__(256) void ln_kernel(
    const u16* __restrict__ x, const float* __restrict__ ln_g,
    const float* __restrict__ ln_b, u16* __restrict__ h)
{
    const int lane = threadIdx.x & 63, wid = threadIdx.x >> 6;
    const int row = blockIdx.x * 4 + wid;
    const int c0 = lane * 4;
    float4 xv = ld4bf(x + (size_t)row * CDIM + c0);
    float s1 = wsum(xv.x + xv.y + xv.z + xv.w);
    float s2 = wsum(xv.x * xv.x + xv.y * xv.y + xv.z * xv.z + xv.w * xv.w);
    const float mean = s1 * (1.f / 256.f);
    const float var  = s2 * (1.f / 256.f) - mean * mean;
    const float rs   = rsqrtf(var + 1e-5f);
    const float4 g = *(const float4*)(ln_g + c0);
    const float4 b = *(const float4*)(ln_b + c0);
    ushort4 hv;
    hv.x = f2bf((xv.x - mean) * rs * g.x + b.x);
    hv.y = f2bf((xv.y - mean) * rs * g.y + b.y);
    hv.z = f2bf((xv.z - mean) * rs * g.z + b.z);
    hv.w = f2bf((xv.w - mean) * rs * g.w + b.w);
    *(ushort4*)(h + (size_t)row * CDIM + c0) = hv;
}

// ---------------------------------------------------------------------------
// GEMM: acc = A[M][KT] @ Bt[NT][KT]^T + bias; 128x128 tile, 4 waves, BK=64,
// double-buffered LDS, T2 XOR swizzle (pre-swizzled global source granule,
// swizzled ds_read; gload_lds LDS dest stays linear).
// MODE 0: Cout=bf16(acc)       1: Cout=bf16(gelu(acc))
//      2: x += gamma*acc (x bf16, in place)
//      3: xnext = x + gamma*acc, scattered bf16 {sdata, srt}
//      4: same as 3 but f32 into fout {data | rt} (final output)
// ---------------------------------------------------------------------------
template<int KT, int NT, int MODE>
__global__ __launch_bounds__(256) void gemm_kernel(
    const u16* __restrict__ A, const u16* __restrict__ Bt,
    const float* __restrict__ bias, u16* __restrict__ Cout,
    u16* __restrict__ xbuf, const float* __restrict__ gamma,
    u16* __restrict__ sdata, u16* __restrict__ srt, float* __restrict__ fout)
{
    __shared__ u16 sm[32768];                 // 64 KB: A dbuf | B dbuf; C-stage
    const int lane = threadIdx.x & 63, wid = threadIdx.x >> 6;
    const int row0 = blockIdx.y * 128, col0 = blockIdx.x * 128;
    const int wr = (wid >> 1) * 64, wc = (wid & 1) * 64;
    const int lr = lane & 15, lg = lane >> 4;
    const int sw = lr & 7;
    f32x4 acc[4][4] = {};
    constexpr int NTk = KT / 64;

    auto STAGE = [&](int t) {
        const int kk0 = t * 64;
        u16* dstA = sm + (t & 1) * 8192;
        u16* dstB = sm + 16384 + (t & 1) * 8192;
#pragma unroll
        for (int cc = 0; cc < 4; ++cc) {
            const int g = wid * 4 + cc;
            const int chunk = g * 64 + lane;
            const int r = chunk >> 3, c8 = chunk & 7;
            const int c8s = c8 ^ (r & 7);     // inverse-swizzled source granule
            gload_lds16(A  + (size_t)(row0 + r) * KT + kk0 + c8s * 8, (char*)dstA + g * 1024);
            gload_lds16(Bt + (size_t)(col0 + r) * KT + kk0 + c8s * 8, (char*)dstB + g * 1024);
        }
    };

    STAGE(0);
    for (int t = 0; t < NTk; ++t) {
        __syncthreads();                      // drains vmcnt: STAGE(t) landed
        if (t + 1 < NTk) STAGE(t + 1);        // overlap next stage with compute
        const u16* Ab = sm + (t & 1) * 8192;
        const u16* Bb = sm + 16384 + (t & 1) * 8192;
#pragma unroll
        for (int kk = 0; kk < 2; ++kk) {
            short8 a[4], b[4];
#pragma unroll
            for (int m = 0; m < 4; ++m)
                a[m] = *(const short8*)(Ab + (wr + m * 16 + lr) * 64 + ((kk * 4 + lg) ^ sw) * 8);
#pragma unroll
            for (int n = 0; n < 4; ++n)
                b[n] = *(const short8*)(Bb + (wc + n * 16 + lr) * 64 + ((kk * 4 + lg) ^ sw) * 8);
#pragma unroll
            for (int m = 0; m < 4; ++m)
#pragma unroll
                for (int n = 0; n < 4; ++n)
                    acc[m][n] = __builtin_amdgcn_mfma_f32_16x16x32_bf16(
                        a[m], b[n], acc[m][n], 0, 0, 0);
        }
    }

    // ---- epilogue: stage bf16 tile in LDS (stride 136 = 17x16B, keeps
    // ds_read_b128 aligned), then fully-coalesced vector stores ------------
    __syncthreads();                          // staging buffers dead now
    u16* Ct = sm;                             // 128*136 = 17408 shorts (34.8KB)
#pragma unroll
    for (int n = 0; n < 4; ++n) {
        const int col = wc + n * 16 + lr;
        const float bv = bias[col0 + col];
#pragma unroll
        for (int m = 0; m < 4; ++m)
#pragma unroll
            for (int r = 0; r < 4; ++r) {
                float v = acc[m][n][r] + bv;
                if (MODE == 1) v = gelu_f(v);
                Ct[(wr + m * 16 + lg * 4 + r) * 136 + col] = f2bf(v);
            }
    }
    __syncthreads();
#pragma unroll
    for (int it = 0; it < 8; ++it) {          // 2048 chunks = 128 rows x 16 gran
        const int c = it * 256 + threadIdx.x;
        const int row = c >> 4, gr = c & 15;
        const int cc0 = col0 + gr * 8;
        short8 v = *(const short8*)(Ct + row * 136 + gr * 8);
        if (MODE <= 1) {
            *(short8*)(Cout + (size_t)(row0 + row) * NT + cc0) = v;
        } else {
            const int grow = row0 + row;
            const float4 g0 = *(const float4*)(gamma + cc0);
            const float4 g1 = *(const float4*)(gamma + cc0 + 4);
            const float gj[8] = {g0.x, g0.y, g0.z, g0.w, g1.x, g1.y, g1.z, g1.w};
            u16* xp = xbuf + (size_t)grow * CDIM + cc0;
            short8 xv = *(const short8*)(xp);
            float xn[8];
#pragma unroll
            for (int j = 0; j < 8; ++j)
                xn[j] = bf2f((u16)xv[j]) + gj[j] * bf2f((u16)v[j]);
            if (MODE == 2) {
                short8 o;
#pragma unroll
                for (int j = 0; j < 8; ++j) o[j] = (short)f2bf(xn[j]);
                *(short8*)xp = o;
            } else {
                const int w = grow / SEQ, s = grow - w * SEQ;
                if (MODE == 3) {
                    u16* dst = (s == 0) ? srt + (size_t)w * CDIM + cc0
                                        : sdata + ((size_t)w * KWIN + s - 1) * CDIM + cc0;
                    short8 o;
#pragma unroll
                    for (int j = 0; j < 8; ++j) o[j] = (short)f2bf(xn[j]);
                    *(short8*)dst = o;
                } else {
                    float* dst = (s == 0) ? fout + (size_t)NTOK * CDIM + (size_t)w * CDIM + cc0
                                          : fout + ((size_t)w * KWIN + s - 1) * CDIM + cc0;
                    *(float4*)dst       = make_float4(xn[0], xn[1], xn[2], xn[3]);
                    *(float4*)(dst + 4) = make_float4(xn[4], xn[5], xn[6], xn[7]);
                }
            }
        }
    }
}

// ---------------------------------------------------------------------------
// K3: MFMA windowed attention (unchanged from round 2).
// ---------------------------------------------------------------------------
__global__ __launch_bounds__(256) void attn_mfma_kernel(
    const u16* __restrict__ qkv, const float* __restrict__ rpe,
    u16* __restrict__ o)
{
    __shared__ u16 sm[4 * 6144];
    const int lane = threadIdx.x & 63, wid = threadIdx.x >> 6;
    u16* Qs = sm + wid * 6144;
    u16* Ks = Qs + 1920;
    u16* Ps = Qs;
    u16* Vt = Qs + 3840;
    const int task = blockIdx.x * 4 + wid;
    const int w = task >> 3, hh = task & 7;
    const u16* base = qkv + (size_t)(w * SEQ) * 768 + hh * 32;

#pragma unroll
    for (int it = 0; it < 5; ++it) {
        int idx = it * 64 + lane;
        if (idx < 288) *(short8*)(Vt + idx * 8) = (short8)0;
    }
#pragma unroll
    for (int it = 0; it < 3; ++it) {
        int idx = it * 64 + lane;
        if (idx < 150) {
            int m = idx >= 75;
            int r = idx - m * 75;
            int s = 33 + r / 5, c = r - (r / 5) * 5;
            *(short8*)((m ? Ks : Qs) + s * 40 + c * 8) = (short8)0;
        }
    }
#pragma unroll
    for (int it = 0; it < 3; ++it) {
        int idx = it * 64 + lane;
        if (idx < 132) {
            int s = idx >> 2, c = idx & 3;
            *(short8*)(Qs + s * 40 + c * 8) = *(const short8*)(base + (size_t)s * 768 + c * 8);
            *(short8*)(Ks + s * 40 + c * 8) = *(const short8*)(base + (size_t)s * 768 + 256 + c * 8);
        }
    }
#pragma unroll
    for (int it = 0; it < 3; ++it) {
        int idx = it * 64 + lane;
        if (idx < 132) {
            int k = idx >> 2, c = idx & 3;
            short8 v = *(const short8*)(base + (size_t)k * 768 + 512 + c * 8);
#pragma unroll
            for (int j = 0; j < 8; ++j) Vt[(c * 8 + j) * 72 + k] = v[j];
        }
    }

    const int lr = lane & 15, lg = lane >> 4;
    short8 qa[3], kb[3];
#pragma unroll
    for (int mi = 0; mi < 3; ++mi)
        qa[mi] = *(const short8*)(Qs + (mi * 16 + lr) * 40 + lg * 8);
#pragma unroll
    for (int ni = 0; ni < 3; ++ni)
        kb[ni] = *(const short8*)(Ks + (ni * 16 + lr) * 40 + lg * 8);
    f32x4 sc[3][3];
#pragma unroll
    for (int mi = 0; mi < 3; ++mi)
#pragma unroll
        for (int ni = 0; ni < 3; ++ni) {
            f32x4 z = {0.f, 0.f, 0.f, 0.f};
            sc[mi][ni] = __builtin_amdgcn_mfma_f32_16x16x32_bf16(qa[mi], kb[ni], z, 0, 0, 0);
        }

    {
        int idx = lane;
        if (idx < 48) {
            *(short8*)(Ps + idx * 72 + 48) = (short8)0;
            *(short8*)(Ps + idx * 72 + 56) = (short8)0;
        }
    }

    const float* rp = rpe + hh * SEQ * SEQ;
    const float scale = 0.17677669529663687f;
#pragma unroll
    for (int mi = 0; mi < 3; ++mi) {
#pragma unroll
        for (int q = 0; q < 4; ++q) {
            const int row = mi * 16 + lg * 4 + q;
            const bool rv_ok = (row < 33);
            float r0 = rv_ok ? rp[row * 33 + lr] : 0.f;
            float r1 = rv_ok ? rp[row * 33 + 16 + lr] : 0.f;
            float r2 = (rv_ok && lr == 0) ? rp[row * 33 + 32] : 0.f;
            float s0 = sc[mi][0][q] * scale + r0;
            float s1 = sc[mi][1][q] * scale + r1;
            float s2 = (lr == 0) ? sc[mi][2][q] * scale + r2 : -1e30f;
            float m = fmaxf(fmaxf(s0, s1), s2);
#pragma unroll
            for (int off = 1; off < 16; off <<= 1) m = fmaxf(m, __shfl_xor(m, off));
            float e0 = __expf(s0 - m), e1 = __expf(s1 - m), e2 = __expf(s2 - m);
            float sum = e0 + e1 + e2;
#pragma unroll
            for (int off = 1; off < 16; off <<= 1) sum += __shfl_xor(sum, off);
            const float inv = 1.f / sum;
            Ps[row * 72 + lr]      = f2bf(e0 * inv);
            Ps[row * 72 + 16 + lr] = f2bf(e1 * inv);
            Ps[row * 72 + 32 + lr] = f2bf(e2 * inv);
        }
    }

    f32x4 oacc[3][2] = {};
#pragma unroll
    for (int ks = 0; ks < 2; ++ks) {
        short8 pa[3], vb[2];
#pragma unroll
        for (int mi = 0; mi < 3; ++mi)
            pa[mi] = *(const short8*)(Ps + (mi * 16 + lr) * 72 + ks * 32 + lg * 8);
#pragma unroll
        for (int ni = 0; ni < 2; ++ni)
            vb[ni] = *(const short8*)(Vt + (ni * 16 + lr) * 72 + ks * 32 + lg * 8);
#pragma unroll
        for (int mi = 0; mi < 3; ++mi)
#pragma unroll
            for (int ni = 0; ni < 2; ++ni)
                oacc[mi][ni] = __builtin_amdgcn_mfma_f32_16x16x32_bf16(
                    pa[mi], vb[ni], oacc[mi][ni], 0, 0, 0);
    }

#pragma unroll
    for (int mi = 0; mi < 3; ++mi)
#pragma unroll
        for (int q = 0; q < 4; ++q) {
            const int row = mi * 16 + lg * 4 + q;
            if (row < 33) {
#pragma unroll
                for (int ni = 0; ni < 2; ++ni)
                    o[(size_t)(w * SEQ + row) * CDIM + hh * 32 + ni * 16 + lr] =
                        f2bf(oacc[mi][ni][q]);
            }
        }
}

// ---------------------------------------------------------------------------
extern "C" void kernel_launch(void* const* d_in, const int* in_sizes, int n_in,
                              void* d_out, int out_size, void* d_ws, size_t ws_size,
                              hipStream_t stream)
{
    const float* data0  = (const float*)d_in[0];
    const float* rt0    = (const float*)d_in[1];
    const float* cpe_w  = (const float*)d_in[2];
    const float* cpe_b  = (const float*)d_in[3];
    const float* ln1_g  = (const float*)d_in[4];
    const float* ln1_b  = (const float*)d_in[5];
    const float* qkv_w  = (const float*)d_in[6];
    const float* qkv_b  = (const float*)d_in[7];
    const float* rpe    = (const float*)d_in[8];
    const float* proj_w = (const float*)d_in[9];
    const float* proj_b = (const float*)d_in[10];
    const float* ln2_g  = (const float*)d_in[11];
    const float* ln2_b  = (const float*)d_in[12];
    const float* w1     = (const float*)d_in[13];
    const float* b1     = (const float*)d_in[14];
    const float* w2     = (const float*)d_in[15];
    const float* b2     = (const float*)d_in[16];
    const float* g1     = (const float*)d_in[17];
    const float* g2     = (const float*)d_in[18];
    float* out = (float*)d_out;

    char* ws = (char*)d_ws;
    u16* regA   = (u16*)ws;
    u16* regB   = (u16*)(ws + 553648128ull);
    u16* x      = (u16*)(ws + 692060160ull);
    u16* xnd    = (u16*)(ws + 830472192ull);
    u16* xnr    = (u16*)(ws + 964689920ull);
    u16* wq_t   = (u16*)(ws + 968884224ull);
    u16* wp_t   = (u16*)(ws + 969670656ull);
    u16* w1_t   = (u16*)(ws + 969932800ull);
    u16* w2_t   = (u16*)(ws + 970981376ull);

    for (int i = 0; i < 2; ++i) {
        transpose_bf16_kernel<<<(256 * 768 + 255) / 256, 256, 0, stream>>>(
            qkv_w + (size_t)i * 256 * 768, wq_t + (size_t)i * 768 * 256, 256, 768);
        transpose_bf16_kernel<<<(256 * 256 + 255) / 256, 256, 0, stream>>>(
            proj_w + (size_t)i * 256 * 256, wp_t + (size_t)i * 256 * 256, 256, 256);
        transpose_bf16_kernel<<<(256 * 1024 + 255) / 256, 256, 0, stream>>>(
            w1 + (size_t)i * 256 * 1024, w1_t + (size_t)i * 1024 * 256, 256, 1024);
        transpose_bf16_kernel<<<(256 * 1024 + 255) / 256, 256, 0, stream>>>(
            w2 + (size_t)i * 1024 * 256, w2_t + (size_t)i * 256 * 1024, 1024, 256);
    }

    for (int i = 0; i < 2; ++i) {
        // 1) CPE + LN1
        if (i == 0)
            cpe_ln1_kernel<false><<<MROWS / 4, 256, 0, stream>>>(
                data0, rt0, cpe_w, cpe_b, ln1_g, ln1_b, x, regB);
        else
            cpe_ln1_kernel<true><<<MROWS / 4, 256, 0, stream>>>(
                xnd, xnr, cpe_w + 3 * 256, cpe_b + 256,
                ln1_g + 256, ln1_b + 256, x, regB);

        // 2) QKV gemm
        gemm_kernel<256, 768, 0><<<dim3(6, MROWS / 128), 256, 0, stream>>>(
            regB, wq_t + (size_t)i * 768 * 256, qkv_b + (size_t)i * 768, regA,
            nullptr, nullptr, nullptr, nullptr, nullptr);

        // 3) windowed attention
        attn_mfma_kernel<<<NW_ * HEADS / 4, 256, 0, stream>>>(
            regA, rpe + (size_t)i * HEADS * SEQ * SEQ, regB);

        // 4) proj gemm, fused: x += g1 * (o@Wp + bp)
        gemm_kernel<256, 256, 2><<<dim3(2, MROWS / 128), 256, 0, stream>>>(
            regB, wp_t + (size_t)i * 256 * 256, proj_b + (size_t)i * 256, nullptr,
            x, g1 + (size_t)i * 256, nullptr, nullptr, nullptr);

        // 5) LN2
        ln_kernel<<<MROWS / 4, 256, 0, stream>>>(
            x, ln2_g + (size_t)i * 256, ln2_b + (size_t)i * 256, regB);

        // 6) MLP1 + GELU
        gemm_kernel<256, 1024, 1><<<dim3(8, MROWS / 128), 256, 0, stream>>>(
            regB, w1_t + (size_t)i * 1024 * 256, b1 + (size_t)i * 1024, regA,
            nullptr, nullptr, nullptr, nullptr, nullptr);

        // 7) MLP2, fused residual + scatter
        if (i == 0)
            gemm_kernel<1024, 256, 3><<<dim3(2, MROWS / 128), 256, 0, stream>>>(
                regA, w2_t, b2, nullptr,
                x, g2, xnd, xnr, nullptr);
        else
            gemm_kernel<1024, 256, 4><<<dim3(2, MROWS / 128), 256, 0, stream>>>(
                regA, w2_t + (size_t)256 * 1024, b2 + 256, nullptr,
                x, g2 + 256, nullptr, nullptr, out);
    }
}

// Round 5
// 2523.134 us; speedup vs baseline: 2.2026x; 1.2049x over previous
//
#include <hip/hip_runtime.h>

// ---------------------------------------------------------------------------
// HOTFormerStage — round 5: GEMM back to m97 single-buffer (34.8 KB LDS ->
// 4 blocks/CU; round-4 dbuf halved occupancy for no pipeline gain), XCD band
// swizzle (col-tiles of one row-tile land on one XCD's L2 -> A fetched once),
// sigmoid-GELU (cheap VALU). Attention + fusions unchanged.
// ---------------------------------------------------------------------------

#define NW_    8192
#define KWIN   32
#define SEQ    33
#define NTOK   262144      // NW_*KWIN
#define MROWS  270336      // NW_*SEQ
#define CDIM   256
#define HEADS  8
#define HIDD   1024

typedef unsigned short u16;
typedef __attribute__((ext_vector_type(8))) short short8;
typedef __attribute__((ext_vector_type(4))) float f32x4;

__device__ __forceinline__ u16 f2bf(float f) {
    unsigned int u = __builtin_bit_cast(unsigned int, f);
    u += 0x7FFFu + ((u >> 16) & 1u);          // RNE
    return (u16)(u >> 16);
}
__device__ __forceinline__ float bf2f(u16 h) {
    return __builtin_bit_cast(float, (unsigned int)h << 16);
}
__device__ __forceinline__ float wsum(float v) {
#pragma unroll
    for (int off = 32; off > 0; off >>= 1) v += __shfl_xor(v, off);
    return v;
}
// gelu(x) ~= x * sigmoid(1.702x); |err| <= ~2e-2, scaled by gamma=1e-5 later.
__device__ __forceinline__ float gelu_f(float v) {
    return v / (1.0f + __expf(-1.702f * v));
}
__device__ __forceinline__ void gload_lds16(const void* g, void* l) {
    __builtin_amdgcn_global_load_lds(
        (const __attribute__((address_space(1))) unsigned int*)g,
        (__attribute__((address_space(3))) unsigned int*)l, 16, 0, 0);
}
__device__ __forceinline__ float4 ld4bf(const u16* p) {
    ushort4 v = *(const ushort4*)p;
    return make_float4(bf2f(v.x), bf2f(v.y), bf2f(v.z), bf2f(v.w));
}

// ---------------------------------------------------------------------------
// K0: weight convert + transpose  W[K][N] f32 -> Wt[N][K] bf16
// ---------------------------------------------------------------------------
__global__ __launch_bounds__(256) void transpose_bf16_kernel(
    const float* __restrict__ W, u16* __restrict__ Wt, int K, int N)
{
    int idx = blockIdx.x * 256 + threadIdx.x;
    if (idx >= K * N) return;
    int n = idx / K, k = idx - n * K;
    Wt[idx] = f2bf(W[(size_t)k * N + n]);
}

// ---------------------------------------------------------------------------
// K1: x = concat(rt, data + cpe_conv(data)) [bf16]; h = LN1(x) [bf16]
// ---------------------------------------------------------------------------
template<bool BF>
__global__ __launch_bounds__(256) void cpe_ln1_kernel(
    const void* __restrict__ datav, const void* __restrict__ rtv,
    const float* __restrict__ cpe_w, const float* __restrict__ cpe_b,
    const float* __restrict__ ln_g, const float* __restrict__ ln_b,
    u16* __restrict__ x, u16* __restrict__ h)
{
    const int lane = threadIdx.x & 63, wid = threadIdx.x >> 6;
    const int row = blockIdx.x * 4 + wid;
    const int w = row / SEQ, s = row - w * SEQ;
    const int c0 = lane * 4;
    float4 xv;
    if (s == 0) {
        xv = BF ? ld4bf((const u16*)rtv + (size_t)w * CDIM + c0)
                : *(const float4*)((const float*)rtv + (size_t)w * CDIM + c0);
    } else {
        const long t = (long)w * KWIN + s - 1;
        float4 a, am = {0.f,0.f,0.f,0.f}, ap = {0.f,0.f,0.f,0.f};
        if (BF) {
            const u16* d = (const u16*)datav;
            a = ld4bf(d + t * CDIM + c0);
            if (t > 0)        am = ld4bf(d + (t - 1) * CDIM + c0);
            if (t < NTOK - 1) ap = ld4bf(d + (t + 1) * CDIM + c0);
        } else {
            const float* d = (const float*)datav;
            a = *(const float4*)(d + t * CDIM + c0);
            if (t > 0)        am = *(const float4*)(d + (t - 1) * CDIM + c0);
            if (t < NTOK - 1) ap = *(const float4*)(d + (t + 1) * CDIM + c0);
        }
        const float4 w0 = *(const float4*)(cpe_w + 0 * CDIM + c0);
        const float4 w1 = *(const float4*)(cpe_w + 1 * CDIM + c0);
        const float4 w2 = *(const float4*)(cpe_w + 2 * CDIM + c0);
        const float4 cb = *(const float4*)(cpe_b + c0);
        xv.x = a.x + am.x * w0.x + a.x * w1.x + ap.x * w2.x + cb.x;
        xv.y = a.y + am.y * w0.y + a.y * w1.y + ap.y * w2.y + cb.y;
        xv.z = a.z + am.z * w0.z + a.z * w1.z + ap.z * w2.z + cb.z;
        xv.w = a.w + am.w * w0.w + a.w * w1.w + ap.w * w2.w + cb.w;
    }
    float s1 = wsum(xv.x + xv.y + xv.z + xv.w);
    float s2 = wsum(xv.x * xv.x + xv.y * xv.y + xv.z * xv.z + xv.w * xv.w);
    const float mean = s1 * (1.f / 256.f);
    const float var  = s2 * (1.f / 256.f) - mean * mean;
    const float rs   = rsqrtf(var + 1e-5f);
    const float4 g = *(const float4*)(ln_g + c0);
    const float4 b = *(const float4*)(ln_b + c0);
    ushort4 xo;
    xo.x = f2bf(xv.x); xo.y = f2bf(xv.y); xo.z = f2bf(xv.z); xo.w = f2bf(xv.w);
    *(ushort4*)(x + (size_t)row * CDIM + c0) = xo;
    ushort4 hv;
    hv.x = f2bf((xv.x - mean) * rs * g.x + b.x);
    hv.y = f2bf((xv.y - mean) * rs * g.y + b.y);
    hv.z = f2bf((xv.z - mean) * rs * g.z + b.z);
    hv.w = f2bf((xv.w - mean) * rs * g.w + b.w);
    *(ushort4*)(h + (size_t)row * CDIM + c0) = hv;
}

// ---------------------------------------------------------------------------
// K_LN: h = LN(x) [bf16 -> bf16]
// ---------------------------------------------------------------------------
__global__ __launch_bounds__(256) void ln_kernel(
    const u16* __restrict__ x, const float* __restrict__ ln_g,
    const float* __restrict__ ln_b, u16* __restrict__ h)
{
    const int lane = threadIdx.x & 63, wid = threadIdx.x >> 6;
    const int row = blockIdx.x * 4 + wid;
    const int c0 = lane * 4;
    float4 xv = ld4bf(x + (size_t)row * CDIM + c0);
    float s1 = wsum(xv.x + xv.y + xv.z + xv.w);
    float s2 = wsum(xv.x * xv.x + xv.y * xv.y + xv.z * xv.z + xv.w * xv.w);
    const float mean = s1 * (1.f / 256.f);
    const float var  = s2 * (1.f / 256.f) - mean * mean;
    const float rs   = rsqrtf(var + 1e-5f);
    const float4 g = *(const float4*)(ln_g + c0);
    const float4 b = *(const float4*)(ln_b + c0);
    ushort4 hv;
    hv.x = f2bf((xv.x - mean) * rs * g.x + b.x);
    hv.y = f2bf((xv.y - mean) * rs * g.y + b.y);
    hv.z = f2bf((xv.z - mean) * rs * g.z + b.z);
    hv.w = f2bf((xv.w - mean) * rs * g.w + b.w);
    *(ushort4*)(h + (size_t)row * CDIM + c0) = hv;
}

// ---------------------------------------------------------------------------
// GEMM: acc = A[M][KT] @ Bt[NT][KT]^T + bias; 128x128 tile, 4 waves, BK=64,
// m97 single-buffer schedule (sync; stage; sync; compute), T2 XOR swizzle.
// 1D grid with XCD band swizzle: xcd = bid&7 owns a contiguous band of
// row-tiles, col-tile varies fastest within the band -> A-tile L2 reuse.
// MODE 0: Cout=bf16(acc)       1: Cout=bf16(gelu(acc))
//      2: x += gamma*acc (x bf16, in place)
//      3: xnext = x + gamma*acc, scattered bf16 {sdata, srt}
//      4: same as 3 but f32 into fout {data | rt} (final output)
// ---------------------------------------------------------------------------
template<int KT, int NT, int MODE>
__global__ __launch_bounds__(256, 4) void gemm_kernel(
    const u16* __restrict__ A, const u16* __restrict__ Bt,
    const float* __restrict__ bias, u16* __restrict__ Cout,
    u16* __restrict__ xbuf, const float* __restrict__ gamma,
    u16* __restrict__ sdata, u16* __restrict__ srt, float* __restrict__ fout)
{
    __shared__ u16 sm[17408];                 // 34.8 KB: stage A|B; epi C-tile
    const int lane = threadIdx.x & 63, wid = threadIdx.x >> 6;
    constexpr int CX = NT / 128;              // col-tiles
    constexpr int BAND = (MROWS / 128) / 8;   // 264 row-tiles per XCD
    const int bid = blockIdx.x;
    const int xcd = bid & 7, local = bid >> 3;
    const int rb = local / CX, cx = local - rb * CX;
    const int row0 = (xcd * BAND + rb) * 128;
    const int col0 = cx * 128;
    const int wr = (wid >> 1) * 64, wc = (wid & 1) * 64;
    const int lr = lane & 15, lg = lane >> 4;
    const int sw = lr & 7;
    f32x4 acc[4][4] = {};
    constexpr int NTk = KT / 64;

    for (int t = 0; t < NTk; ++t) {
        const int kk0 = t * 64;
        __syncthreads();                      // prior compute done reading LDS
#pragma unroll
        for (int cc = 0; cc < 4; ++cc) {
            const int g = wid * 4 + cc;
            const int chunk = g * 64 + lane;
            const int r = chunk >> 3, c8 = chunk & 7;
            const int c8s = c8 ^ (r & 7);     // inverse-swizzled source granule
            gload_lds16(A  + (size_t)(row0 + r) * KT + kk0 + c8s * 8, (char*)sm + g * 1024);
            gload_lds16(Bt + (size_t)(col0 + r) * KT + kk0 + c8s * 8, (char*)sm + 16384 + g * 1024);
        }
        __syncthreads();                      // drains vmcnt: stage landed
        const u16* Ab = sm;
        const u16* Bb = sm + 8192;
#pragma unroll
        for (int kk = 0; kk < 2; ++kk) {
            short8 a[4], b[4];
#pragma unroll
            for (int m = 0; m < 4; ++m)
                a[m] = *(const short8*)(Ab + (wr + m * 16 + lr) * 64 + ((kk * 4 + lg) ^ sw) * 8);
#pragma unroll
            for (int n = 0; n < 4; ++n)
                b[n] = *(const short8*)(Bb + (wc + n * 16 + lr) * 64 + ((kk * 4 + lg) ^ sw) * 8);
#pragma unroll
            for (int m = 0; m < 4; ++m)
#pragma unroll
                for (int n = 0; n < 4; ++n)
                    acc[m][n] = __builtin_amdgcn_mfma_f32_16x16x32_bf16(
                        a[m], b[n], acc[m][n], 0, 0, 0);
        }
    }

    // ---- epilogue: stage bf16 tile in LDS (stride 136 = 17x16B), then
    // fully-coalesced vector stores ----------------------------------------
    __syncthreads();                          // staging area dead now
    u16* Ct = sm;                             // 128*136 = 17408 shorts
#pragma unroll
    for (int n = 0; n < 4; ++n) {
        const int col = wc + n * 16 + lr;
        const float bv = bias[col0 + col];
#pragma unroll
        for (int m = 0; m < 4; ++m)
#pragma unroll
            for (int r = 0; r < 4; ++r) {
                float v = acc[m][n][r] + bv;
                if (MODE == 1) v = gelu_f(v);
                Ct[(wr + m * 16 + lg * 4 + r) * 136 + col] = f2bf(v);
            }
    }
    __syncthreads();
#pragma unroll
    for (int it = 0; it < 8; ++it) {          // 2048 chunks = 128 rows x 16 gran
        const int c = it * 256 + threadIdx.x;
        const int row = c >> 4, gr = c & 15;
        const int cc0 = col0 + gr * 8;
        short8 v = *(const short8*)(Ct + row * 136 + gr * 8);
        if (MODE <= 1) {
            *(short8*)(Cout + (size_t)(row0 + row) * NT + cc0) = v;
        } else {
            const int grow = row0 + row;
            const float4 g0 = *(const float4*)(gamma + cc0);
            const float4 g1 = *(const float4*)(gamma + cc0 + 4);
            const float gj[8] = {g0.x, g0.y, g0.z, g0.w, g1.x, g1.y, g1.z, g1.w};
            u16* xp = xbuf + (size_t)grow * CDIM + cc0;
            short8 xv = *(const short8*)(xp);
            float xn[8];
#pragma unroll
            for (int j = 0; j < 8; ++j)
                xn[j] = bf2f((u16)xv[j]) + gj[j] * bf2f((u16)v[j]);
            if (MODE == 2) {
                short8 o;
#pragma unroll
                for (int j = 0; j < 8; ++j) o[j] = (short)f2bf(xn[j]);
                *(short8*)xp = o;
            } else {
                const int w = grow / SEQ, s = grow - w * SEQ;
                if (MODE == 3) {
                    u16* dst = (s == 0) ? srt + (size_t)w * CDIM + cc0
                                        : sdata + ((size_t)w * KWIN + s - 1) * CDIM + cc0;
                    short8 o;
#pragma unroll
                    for (int j = 0; j < 8; ++j) o[j] = (short)f2bf(xn[j]);
                    *(short8*)dst = o;
                } else {
                    float* dst = (s == 0) ? fout + (size_t)NTOK * CDIM + (size_t)w * CDIM + cc0
                                          : fout + ((size_t)w * KWIN + s - 1) * CDIM + cc0;
                    *(float4*)dst       = make_float4(xn[0], xn[1], xn[2], xn[3]);
                    *(float4*)(dst + 4) = make_float4(xn[4], xn[5], xn[6], xn[7]);
                }
            }
        }
    }
}

// ---------------------------------------------------------------------------
// K3: MFMA windowed attention (unchanged from round 2).
// ---------------------------------------------------------------------------
__global__ __launch_bounds__(256) void attn_mfma_kernel(
    const u16* __restrict__ qkv, const float* __restrict__ rpe,
    u16* __restrict__ o)
{
    __shared__ u16 sm[4 * 6144];
    const int lane = threadIdx.x & 63, wid = threadIdx.x >> 6;
    u16* Qs = sm + wid * 6144;
    u16* Ks = Qs + 1920;
    u16* Ps = Qs;
    u16* Vt = Qs + 3840;
    const int task = blockIdx.x * 4 + wid;
    const int w = task >> 3, hh = task & 7;
    const u16* base = qkv + (size_t)(w * SEQ) * 768 + hh * 32;

#pragma unroll
    for (int it = 0; it < 5; ++it) {
        int idx = it * 64 + lane;
        if (idx < 288) *(short8*)(Vt + idx * 8) = (short8)0;
    }
#pragma unroll
    for (int it = 0; it < 3; ++it) {
        int idx = it * 64 + lane;
        if (idx < 150) {
            int m = idx >= 75;
            int r = idx - m * 75;
            int s = 33 + r / 5, c = r - (r / 5) * 5;
            *(short8*)((m ? Ks : Qs) + s * 40 + c * 8) = (short8)0;
        }
    }
#pragma unroll
    for (int it = 0; it < 3; ++it) {
        int idx = it * 64 + lane;
        if (idx < 132) {
            int s = idx >> 2, c = idx & 3;
            *(short8*)(Qs + s * 40 + c * 8) = *(const short8*)(base + (size_t)s * 768 + c * 8);
            *(short8*)(Ks + s * 40 + c * 8) = *(const short8*)(base + (size_t)s * 768 + 256 + c * 8);
        }
    }
#pragma unroll
    for (int it = 0; it < 3; ++it) {
        int idx = it * 64 + lane;
        if (idx < 132) {
            int k = idx >> 2, c = idx & 3;
            short8 v = *(const short8*)(base + (size_t)k * 768 + 512 + c * 8);
#pragma unroll
            for (int j = 0; j < 8; ++j) Vt[(c * 8 + j) * 72 + k] = v[j];
        }
    }

    const int lr = lane & 15, lg = lane >> 4;
    short8 qa[3], kb[3];
#pragma unroll
    for (int mi = 0; mi < 3; ++mi)
        qa[mi] = *(const short8*)(Qs + (mi * 16 + lr) * 40 + lg * 8);
#pragma unroll
    for (int ni = 0; ni < 3; ++ni)
        kb[ni] = *(const short8*)(Ks + (ni * 16 + lr) * 40 + lg * 8);
    f32x4 sc[3][3];
#pragma unroll
    for (int mi = 0; mi < 3; ++mi)
#pragma unroll
        for (int ni = 0; ni < 3; ++ni) {
            f32x4 z = {0.f, 0.f, 0.f, 0.f};
            sc[mi][ni] = __builtin_amdgcn_mfma_f32_16x16x32_bf16(qa[mi], kb[ni], z, 0, 0, 0);
        }

    {
        int idx = lane;
        if (idx < 48) {
            *(short8*)(Ps + idx * 72 + 48) = (short8)0;
            *(short8*)(Ps + idx * 72 + 56) = (short8)0;
        }
    }

    const float* rp = rpe + hh * SEQ * SEQ;
    const float scale = 0.17677669529663687f;
#pragma unroll
    for (int mi = 0; mi < 3; ++mi) {
#pragma unroll
        for (int q = 0; q < 4; ++q) {
            const int row = mi * 16 + lg * 4 + q;
            const bool rv_ok = (row < 33);
            float r0 = rv_ok ? rp[row * 33 + lr] : 0.f;
            float r1 = rv_ok ? rp[row * 33 + 16 + lr] : 0.f;
            float r2 = (rv_ok && lr == 0) ? rp[row * 33 + 32] : 0.f;
            float s0 = sc[mi][0][q] * scale + r0;
            float s1 = sc[mi][1][q] * scale + r1;
            float s2 = (lr == 0) ? sc[mi][2][q] * scale + r2 : -1e30f;
            float m = fmaxf(fmaxf(s0, s1), s2);
#pragma unroll
            for (int off = 1; off < 16; off <<= 1) m = fmaxf(m, __shfl_xor(m, off));
            float e0 = __expf(s0 - m), e1 = __expf(s1 - m), e2 = __expf(s2 - m);
            float sum = e0 + e1 + e2;
#pragma unroll
            for (int off = 1; off < 16; off <<= 1) sum += __shfl_xor(sum, off);
            const float inv = 1.f / sum;
            Ps[row * 72 + lr]      = f2bf(e0 * inv);
            Ps[row * 72 + 16 + lr] = f2bf(e1 * inv);
            Ps[row * 72 + 32 + lr] = f2bf(e2 * inv);
        }
    }

    f32x4 oacc[3][2] = {};
#pragma unroll
    for (int ks = 0; ks < 2; ++ks) {
        short8 pa[3], vb[2];
#pragma unroll
        for (int mi = 0; mi < 3; ++mi)
            pa[mi] = *(const short8*)(Ps + (mi * 16 + lr) * 72 + ks * 32 + lg * 8);
#pragma unroll
        for (int ni = 0; ni < 2; ++ni)
            vb[ni] = *(const short8*)(Vt + (ni * 16 + lr) * 72 + ks * 32 + lg * 8);
#pragma unroll
        for (int mi = 0; mi < 3; ++mi)
#pragma unroll
            for (int ni = 0; ni < 2; ++ni)
                oacc[mi][ni] = __builtin_amdgcn_mfma_f32_16x16x32_bf16(
                    pa[mi], vb[ni], oacc[mi][ni], 0, 0, 0);
    }

#pragma unroll
    for (int mi = 0; mi < 3; ++mi)
#pragma unroll
        for (int q = 0; q < 4; ++q) {
            const int row = mi * 16 + lg * 4 + q;
            if (row < 33) {
#pragma unroll
                for (int ni = 0; ni < 2; ++ni)
                    o[(size_t)(w * SEQ + row) * CDIM + hh * 32 + ni * 16 + lr] =
                        f2bf(oacc[mi][ni][q]);
            }
        }
}

// ---------------------------------------------------------------------------
extern "C" void kernel_launch(void* const* d_in, const int* in_sizes, int n_in,
                              void* d_out, int out_size, void* d_ws, size_t ws_size,
                              hipStream_t stream)
{
    const float* data0  = (const float*)d_in[0];
    const float* rt0    = (const float*)d_in[1];
    const float* cpe_w  = (const float*)d_in[2];
    const float* cpe_b  = (const float*)d_in[3];
    const float* ln1_g  = (const float*)d_in[4];
    const float* ln1_b  = (const float*)d_in[5];
    const float* qkv_w  = (const float*)d_in[6];
    const float* qkv_b  = (const float*)d_in[7];
    const float* rpe    = (const float*)d_in[8];
    const float* proj_w = (const float*)d_in[9];
    const float* proj_b = (const float*)d_in[10];
    const float* ln2_g  = (const float*)d_in[11];
    const float* ln2_b  = (const float*)d_in[12];
    const float* w1     = (const float*)d_in[13];
    const float* b1     = (const float*)d_in[14];
    const float* w2     = (const float*)d_in[15];
    const float* b2     = (const float*)d_in[16];
    const float* g1     = (const float*)d_in[17];
    const float* g2     = (const float*)d_in[18];
    float* out = (float*)d_out;

    char* ws = (char*)d_ws;
    u16* regA   = (u16*)ws;
    u16* regB   = (u16*)(ws + 553648128ull);
    u16* x      = (u16*)(ws + 692060160ull);
    u16* xnd    = (u16*)(ws + 830472192ull);
    u16* xnr    = (u16*)(ws + 964689920ull);
    u16* wq_t   = (u16*)(ws + 968884224ull);
    u16* wp_t   = (u16*)(ws + 969670656ull);
    u16* w1_t   = (u16*)(ws + 969932800ull);
    u16* w2_t   = (u16*)(ws + 970981376ull);

    for (int i = 0; i < 2; ++i) {
        transpose_bf16_kernel<<<(256 * 768 + 255) / 256, 256, 0, stream>>>(
            qkv_w + (size_t)i * 256 * 768, wq_t + (size_t)i * 768 * 256, 256, 768);
        transpose_bf16_kernel<<<(256 * 256 + 255) / 256, 256, 0, stream>>>(
            proj_w + (size_t)i * 256 * 256, wp_t + (size_t)i * 256 * 256, 256, 256);
        transpose_bf16_kernel<<<(256 * 1024 + 255) / 256, 256, 0, stream>>>(
            w1 + (size_t)i * 256 * 1024, w1_t + (size_t)i * 1024 * 256, 256, 1024);
        transpose_bf16_kernel<<<(256 * 1024 + 255) / 256, 256, 0, stream>>>(
            w2 + (size_t)i * 1024 * 256, w2_t + (size_t)i * 256 * 1024, 1024, 256);
    }

    const int RT = MROWS / 128;               // 2112 row-tiles

    for (int i = 0; i < 2; ++i) {
        // 1) CPE + LN1
        if (i == 0)
            cpe_ln1_kernel<false><<<MROWS / 4, 256, 0, stream>>>(
                data0, rt0, cpe_w, cpe_b, ln1_g, ln1_b, x, regB);
        else
            cpe_ln1_kernel<true><<<MROWS / 4, 256, 0, stream>>>(
                xnd, xnr, cpe_w + 3 * 256, cpe_b + 256,
                ln1_g + 256, ln1_b + 256, x, regB);

        // 2) QKV gemm
        gemm_kernel<256, 768, 0><<<RT * 6, 256, 0, stream>>>(
            regB, wq_t + (size_t)i * 768 * 256, qkv_b + (size_t)i * 768, regA,
            nullptr, nullptr, nullptr, nullptr, nullptr);

        // 3) windowed attention
        attn_mfma_kernel<<<NW_ * HEADS / 4, 256, 0, stream>>>(
            regA, rpe + (size_t)i * HEADS * SEQ * SEQ, regB);

        // 4) proj gemm, fused: x += g1 * (o@Wp + bp)
        gemm_kernel<256, 256, 2><<<RT * 2, 256, 0, stream>>>(
            regB, wp_t + (size_t)i * 256 * 256, proj_b + (size_t)i * 256, nullptr,
            x, g1 + (size_t)i * 256, nullptr, nullptr, nullptr);

        // 5) LN2
        ln_kernel<<<MROWS / 4, 256, 0, stream>>>(
            x, ln2_g + (size_t)i * 256, ln2_b + (size_t)i * 256, regB);

        // 6) MLP1 + GELU
        gemm_kernel<256, 1024, 1><<<RT * 8, 256, 0, stream>>>(
            regB, w1_t + (size_t)i * 1024 * 256, b1 + (size_t)i * 1024, regA,
            nullptr, nullptr, nullptr, nullptr, nullptr);

        // 7) MLP2, fused residual + scatter
        if (i == 0)
            gemm_kernel<1024, 256, 3><<<RT * 2, 256, 0, stream>>>(
                regA, w2_t, b2, nullptr,
                x, g2, xnd, xnr, nullptr);
        else
            gemm_kernel<1024, 256, 4><<<RT * 2, 256, 0, stream>>>(
                regA, w2_t + (size_t)256 * 1024, b2 + 256, nullptr,
                x, g2 + 256, nullptr, nullptr, out);
    }
}